// Round 1
// baseline (529.250 us; speedup 1.0000x reference)
//
#include <hip/hip_runtime.h>
#include <math.h>

// Problem shape (fixed by reference setup_inputs)
#define BATCH 32
#define SEQ   4096
#define HID   768
#define HV4   (HID / 4)                       // 192 float4 per row
#define CHUNKS 64                             // chunks per batch
#define ROWS_PER_BLOCK (SEQ / CHUNKS)         // 64
#define NWAVES 4
#define ROWS_PER_WAVE (ROWS_PER_BLOCK / NWAVES) // 16

__device__ __forceinline__ float dot4(float4 a, float4 b) {
  return a.x * b.x + a.y * b.y + a.z * b.z + a.w * b.w;
}

// Pass 1: one block per (chunk, batch). Each wave runs online softmax over its
// 16 rows; rows are read ONCE (dot + accumulate from the same registers).
// Block combines 4 wave partials in LDS, writes (m, l, O[768]) per chunk.
__global__ __launch_bounds__(256, 4)
void attn_pass1(const float* __restrict__ hidden,
                const float* __restrict__ q,
                float* __restrict__ m_ws,
                float* __restrict__ l_ws,
                float* __restrict__ o_ws) {
  const int chunk = blockIdx.x;
  const int b     = blockIdx.y;
  const int tid   = threadIdx.x;
  const int wave  = tid >> 6;
  const int lane  = tid & 63;

  // Query fragment for this lane: h = 4*lane..4*lane+3, +256, +512
  const float4* q4 = reinterpret_cast<const float4*>(q);
  const float4 qa = q4[lane];
  const float4 qb = q4[lane + 64];
  const float4 qc = q4[lane + 128];

  float m = -INFINITY;
  float l = 0.0f;
  float4 oa = make_float4(0.f, 0.f, 0.f, 0.f);
  float4 ob = make_float4(0.f, 0.f, 0.f, 0.f);
  float4 oc = make_float4(0.f, 0.f, 0.f, 0.f);

  const int row0 = chunk * ROWS_PER_BLOCK + wave * ROWS_PER_WAVE;
  const float4* base = reinterpret_cast<const float4*>(hidden)
                     + ((size_t)b * SEQ + (size_t)row0) * HV4;

  for (int i = 0; i < ROWS_PER_WAVE; ++i) {
    const float4* rp = base + (size_t)i * HV4;
    const float4 ra = rp[lane];
    const float4 rb = rp[lane + 64];
    const float4 rc = rp[lane + 128];

    float pd = dot4(ra, qa) + dot4(rb, qb) + dot4(rc, qc);
    // 64-lane butterfly sum -> score is wave-uniform afterwards
    #pragma unroll
    for (int off = 32; off >= 1; off >>= 1)
      pd += __shfl_xor(pd, off, 64);
    const float w = pd;

    if (w > m) {                 // wave-uniform branch (w identical on all lanes)
      const float a = __expf(m - w);   // exp(-inf)=0 on first row: zeroes stay zero
      l *= a;
      oa.x *= a; oa.y *= a; oa.z *= a; oa.w *= a;
      ob.x *= a; ob.y *= a; ob.z *= a; ob.w *= a;
      oc.x *= a; oc.y *= a; oc.z *= a; oc.w *= a;
      m = w;
    }
    const float p = __expf(w - m);
    l += p;
    oa.x += p * ra.x; oa.y += p * ra.y; oa.z += p * ra.z; oa.w += p * ra.w;
    ob.x += p * rb.x; ob.y += p * rb.y; ob.z += p * rb.z; ob.w += p * rb.w;
    oc.x += p * rc.x; oc.y += p * rc.y; oc.z += p * rc.z; oc.w += p * rc.w;
  }

  // Combine the 4 wave partials in LDS
  __shared__ float s_o[NWAVES][HID];   // 12 KB
  __shared__ float s_m[NWAVES];
  __shared__ float s_l[NWAVES];
  float4* so4 = reinterpret_cast<float4*>(s_o[wave]);
  so4[lane]       = oa;
  so4[lane + 64]  = ob;
  so4[lane + 128] = oc;
  if (lane == 0) { s_m[wave] = m; s_l[wave] = l; }
  __syncthreads();

  const float mb = fmaxf(fmaxf(s_m[0], s_m[1]), fmaxf(s_m[2], s_m[3]));
  const float a0 = __expf(s_m[0] - mb);
  const float a1 = __expf(s_m[1] - mb);
  const float a2 = __expf(s_m[2] - mb);
  const float a3 = __expf(s_m[3] - mb);
  const float lb = a0 * s_l[0] + a1 * s_l[1] + a2 * s_l[2] + a3 * s_l[3];

  const int pidx = b * CHUNKS + chunk;
  float* O = o_ws + (size_t)pidx * HID;
  #pragma unroll
  for (int j = 0; j < 3; ++j) {
    const int h = tid + 256 * j;
    O[h] = a0 * s_o[0][h] + a1 * s_o[1][h] + a2 * s_o[2][h] + a3 * s_o[3][h];
  }
  if (tid == 0) { m_ws[pidx] = mb; l_ws[pidx] = lb; }
}

// Pass 2: one block per batch; merge the 64 chunk partials and normalize.
__global__ __launch_bounds__(256)
void attn_pass2(const float* __restrict__ m_ws,
                const float* __restrict__ l_ws,
                const float* __restrict__ o_ws,
                float* __restrict__ out) {
  const int b   = blockIdx.x;
  const int tid = threadIdx.x;

  float mg = -INFINITY;
  for (int c = 0; c < CHUNKS; ++c)
    mg = fmaxf(mg, m_ws[b * CHUNKS + c]);

  float L = 0.0f;
  float acc0 = 0.f, acc1 = 0.f, acc2 = 0.f;
  for (int c = 0; c < CHUNKS; ++c) {
    const int pidx = b * CHUNKS + c;
    const float a = __expf(m_ws[pidx] - mg);
    L += a * l_ws[pidx];
    const float* O = o_ws + (size_t)pidx * HID;
    acc0 += a * O[tid];
    acc1 += a * O[tid + 256];
    acc2 += a * O[tid + 512];
  }
  const float inv = 1.0f / L;
  out[(size_t)b * HID + tid]       = acc0 * inv;
  out[(size_t)b * HID + tid + 256] = acc1 * inv;
  out[(size_t)b * HID + tid + 512] = acc2 * inv;
}

extern "C" void kernel_launch(void* const* d_in, const int* in_sizes, int n_in,
                              void* d_out, int out_size, void* d_ws, size_t ws_size,
                              hipStream_t stream) {
  const float* hidden = (const float*)d_in[0];   // [32, 4096, 768] fp32
  const float* q      = (const float*)d_in[1];   // [1, 768] fp32
  float* out = (float*)d_out;                    // [32, 768] fp32

  // Workspace layout: m[2048] | l[2048] | O[2048*768]  (~6.3 MB total)
  float* m_ws = (float*)d_ws;
  float* l_ws = m_ws + BATCH * CHUNKS;
  float* o_ws = l_ws + BATCH * CHUNKS;

  dim3 grid1(CHUNKS, BATCH);
  attn_pass1<<<grid1, 256, 0, stream>>>(hidden, q, m_ws, l_ws, o_ws);
  attn_pass2<<<BATCH, 256, 0, stream>>>(m_ws, l_ws, o_ws, out);
}